// Round 5
// baseline (887.779 us; speedup 1.0000x reference)
//
#include <hip/hip_runtime.h>
#include <math.h>

#define N_NODES 50000
#define N_EDGES 800000
#define N_GRAPHS 512
#define D 64
#define DE 32

// ---------------------------------------------------------------------------
// T table layout per node n (256 floats):
//   T[n*256 +   0 + j] = Af[n][j] = x[n] @ Wf[0:64]  + bf[j]   (dst part, f)
//   T[n*256 +  64 + j] = As[n][j] = x[n] @ Ws[0:64]  + bs[j]   (dst part, s)
//   T[n*256 + 128 + j] = Bf[n][j] = x[n] @ Wf[64:128]          (src part, f)
//   T[n*256 + 192 + j] = Bs[n][j] = x[n] @ Ws[64:128]          (src part, s)
//
// R2 lesson: private arrays demoted to scratch by SROA -> named float4 SSA.
// R4 lesson: SSA alone insufficient — AMDGPU PreRARemat sinks read-only loads
// back into the loop chasing occupancy (VGPR stayed 48, ~500 instr/edge).
// R5 fix: amdgpu_waves_per_eu(4,4) pins the occupancy target AND an empty
// asm volatile "+v" pin makes the 64 weight values non-rematerializable.
// ---------------------------------------------------------------------------

// load 4 weight-column entries (row stride 64) into one float4
#define LDW(vec, base, c0)                         \
    vec.x = (base)[((c0) + 0) * 64 + lane];        \
    vec.y = (base)[((c0) + 1) * 64 + lane];        \
    vec.z = (base)[((c0) + 2) * 64 + lane];        \
    vec.w = (base)[((c0) + 3) * 64 + lane];

// pin 4 floats (one float4) as asm-defined -> not rematerializable
#define PIN4(vec) \
    asm volatile("" : "+v"(vec.x), "+v"(vec.y), "+v"(vec.z), "+v"(vec.w));

__global__ __attribute__((amdgpu_flat_work_group_size(256, 256),
                          amdgpu_waves_per_eu(4, 4)))
void node_transform(
    const float* __restrict__ H,          // [N_NODES][64]
    const float* __restrict__ Wf,         // [160][64]
    const float* __restrict__ Ws,         // [160][64]
    const float* __restrict__ bf,         // [64]
    const float* __restrict__ bs,         // [64]
    float* __restrict__ T)                // [N_NODES][256]
{
    const int lane = threadIdx.x & 63;
    const int tbl  = (threadIdx.x >> 6) & 3;  // 0:Af 1:As 2:Bf 3:Bs

    const float* W = (tbl == 0 || tbl == 2) ? Wf : Ws;
    const float* Wb = W + ((tbl < 2) ? 0 : 64 * 64);

    float4 w0, w1, w2, w3, w4, w5, w6, w7, w8, w9, w10, w11, w12, w13, w14, w15;
    LDW(w0,  Wb,  0) LDW(w1,  Wb,  4) LDW(w2,  Wb,  8) LDW(w3,  Wb, 12)
    LDW(w4,  Wb, 16) LDW(w5,  Wb, 20) LDW(w6,  Wb, 24) LDW(w7,  Wb, 28)
    LDW(w8,  Wb, 32) LDW(w9,  Wb, 36) LDW(w10, Wb, 40) LDW(w11, Wb, 44)
    LDW(w12, Wb, 48) LDW(w13, Wb, 52) LDW(w14, Wb, 56) LDW(w15, Wb, 60)
    PIN4(w0)  PIN4(w1)  PIN4(w2)  PIN4(w3)
    PIN4(w4)  PIN4(w5)  PIN4(w6)  PIN4(w7)
    PIN4(w8)  PIN4(w9)  PIN4(w10) PIN4(w11)
    PIN4(w12) PIN4(w13) PIN4(w14) PIN4(w15)

    float bias = 0.0f;
    if (tbl == 0) bias = bf[lane];
    else if (tbl == 1) bias = bs[lane];

#define NT4(i, wv)                                    \
    { float4 v = xr[i];                               \
      acc0 = fmaf(v.x, wv.x, acc0);                   \
      acc1 = fmaf(v.y, wv.y, acc1);                   \
      acc0 = fmaf(v.z, wv.z, acc0);                   \
      acc1 = fmaf(v.w, wv.w, acc1); }

    for (int n = blockIdx.x; n < N_NODES; n += gridDim.x) {
        const float4* xr = (const float4*)(H + (size_t)n * D);
        float acc0 = bias, acc1 = 0.0f;
        NT4(0, w0)   NT4(1, w1)   NT4(2, w2)   NT4(3, w3)
        NT4(4, w4)   NT4(5, w5)   NT4(6, w6)   NT4(7, w7)
        NT4(8, w8)   NT4(9, w9)   NT4(10, w10) NT4(11, w11)
        NT4(12, w12) NT4(13, w13) NT4(14, w14) NT4(15, w15)
        T[(size_t)n * 256 + tbl * 64 + lane] = acc0 + acc1;
    }
#undef NT4
}

// One wave per edge (grid-strided). Lane j computes output channel j.
__global__ __attribute__((amdgpu_flat_work_group_size(256, 256),
                          amdgpu_waves_per_eu(4, 4)))
void edge_message(
    const float* __restrict__ T,          // [N_NODES][256]
    const int* __restrict__ ei,           // [2][N_EDGES]
    const float* __restrict__ ea,         // [N_EDGES][32]
    const float* __restrict__ Wf,         // [160][64] (rows 128..159 used)
    const float* __restrict__ Ws,
    float* __restrict__ hout)             // [N_NODES][64], pre-init to input h
{
    const int lane = threadIdx.x & 63;
    const int wid  = threadIdx.x >> 6;

    // edge-attr weight columns: 16 named float4 = 64 VGPRs, asm-pinned
    const float* Wfe = Wf + 128 * 64;
    const float* Wse = Ws + 128 * 64;
    float4 f0, f1, f2, f3, f4, f5, f6, f7;
    float4 s0, s1, s2, s3, s4, s5, s6, s7;
    LDW(f0, Wfe,  0) LDW(f1, Wfe,  4) LDW(f2, Wfe,  8) LDW(f3, Wfe, 12)
    LDW(f4, Wfe, 16) LDW(f5, Wfe, 20) LDW(f6, Wfe, 24) LDW(f7, Wfe, 28)
    LDW(s0, Wse,  0) LDW(s1, Wse,  4) LDW(s2, Wse,  8) LDW(s3, Wse, 12)
    LDW(s4, Wse, 16) LDW(s5, Wse, 20) LDW(s6, Wse, 24) LDW(s7, Wse, 28)
    PIN4(f0) PIN4(f1) PIN4(f2) PIN4(f3)
    PIN4(f4) PIN4(f5) PIN4(f6) PIN4(f7)
    PIN4(s0) PIN4(s1) PIN4(s2) PIN4(s3)
    PIN4(s4) PIN4(s5) PIN4(s6) PIN4(s7)

#define RL(c) __int_as_float(__builtin_amdgcn_readlane(ieav, (c)))
#define EDGE4(c0, vf, vs)                                           \
    { float z0 = RL(c0 + 0), z1 = RL(c0 + 1);                       \
      float z2 = RL(c0 + 2), z3 = RL(c0 + 3);                       \
      accf0 = fmaf(z0, vf.x, accf0); accs0 = fmaf(z0, vs.x, accs0); \
      accf1 = fmaf(z1, vf.y, accf1); accs1 = fmaf(z1, vs.y, accs1); \
      accf0 = fmaf(z2, vf.z, accf0); accs0 = fmaf(z2, vs.z, accs0); \
      accf1 = fmaf(z3, vf.w, accf1); accs1 = fmaf(z3, vs.w, accs1); }

    const int nwaves = gridDim.x * 4;
    for (int e0 = blockIdx.x * 4 + wid; e0 < N_EDGES; e0 += nwaves) {
        const int e   = __builtin_amdgcn_readfirstlane(e0);
        const int src = ei[e];
        const int dst = ei[N_EDGES + e];

        const float* td = T + (size_t)dst * 256;
        const float* ts = T + (size_t)src * 256;

        float a0  = td[lane];          // Af[dst] (+bf folded)
        float a1  = td[64 + lane];     // As[dst] (+bs folded)
        float b0  = ts[128 + lane];    // Bf[src]
        float b1  = ts[192 + lane];    // Bs[src]
        float eav = ea[(size_t)e * DE + (lane & (DE - 1))];
        int  ieav = __float_as_int(eav);

        float accf0 = a0, accf1 = b0;
        float accs0 = a1, accs1 = b1;
        EDGE4(0,  f0, s0) EDGE4(4,  f1, s1) EDGE4(8,  f2, s2) EDGE4(12, f3, s3)
        EDGE4(16, f4, s4) EDGE4(20, f5, s5) EDGE4(24, f6, s6) EDGE4(28, f7, s7)
        float accf = accf0 + accf1;
        float accs = accs0 + accs1;

        // sigmoid(accf) * softplus(accs), numerically stable
        float sig = 1.0f / (1.0f + __expf(-accf));
        float sp  = fmaxf(accs, 0.0f) + log1pf(__expf(-fabsf(accs)));
        atomicAdd(&hout[(size_t)dst * D + lane], sig * sp);
    }
#undef EDGE4
#undef RL
}

// segment_sum(h, batch) into pooled[N_GRAPHS][64]
__global__ __launch_bounds__(256) void pool_kernel(
    const float* __restrict__ h,          // [N_NODES][64]
    const int* __restrict__ batch,        // [N_NODES]
    float* __restrict__ pooled)           // [N_GRAPHS][64], pre-zeroed
{
    const int lane = threadIdx.x & 63;
    const int wid  = threadIdx.x >> 6;
    const int nwaves = gridDim.x * 4;
    for (int n = blockIdx.x * 4 + wid; n < N_NODES; n += nwaves) {
        const int g = batch[n];
        atomicAdd(&pooled[(size_t)g * D + lane], h[(size_t)n * D + lane]);
    }
}

__global__ __launch_bounds__(256) void out_kernel(
    const float* __restrict__ pooled,     // [N_GRAPHS][64]
    const float* __restrict__ Wout,       // [64]
    const float* __restrict__ bout,       // [1]
    float* __restrict__ out)              // [N_GRAPHS]
{
    const int g = blockIdx.x * blockDim.x + threadIdx.x;
    if (g >= N_GRAPHS) return;
    float acc = bout[0];
#pragma unroll
    for (int j = 0; j < D; ++j) acc = fmaf(pooled[(size_t)g * D + j], Wout[j], acc);
    out[g] = acc;
}

extern "C" void kernel_launch(void* const* d_in, const int* in_sizes, int n_in,
                              void* d_out, int out_size, void* d_ws, size_t ws_size,
                              hipStream_t stream) {
    const float* x     = (const float*)d_in[0];
    const int*   ei    = (const int*)  d_in[1];
    const float* ea    = (const float*)d_in[2];
    const int*   batch = (const int*)  d_in[3];
    const float* Wf1   = (const float*)d_in[4];
    const float* bf1   = (const float*)d_in[5];
    const float* Ws1   = (const float*)d_in[6];
    const float* bs1   = (const float*)d_in[7];
    const float* Wf2   = (const float*)d_in[8];
    const float* bf2   = (const float*)d_in[9];
    const float* Ws2   = (const float*)d_in[10];
    const float* bs2   = (const float*)d_in[11];
    const float* Wout  = (const float*)d_in[12];
    const float* bout  = (const float*)d_in[13];
    float* out = (float*)d_out;

    // workspace layout
    float* T      = (float*)d_ws;                       // 50000*256
    float* h1     = T + (size_t)N_NODES * 256;          // 50000*64
    float* h2     = h1 + (size_t)N_NODES * D;           // 50000*64
    float* pooled = h2 + (size_t)N_NODES * D;           // 512*64

    const int GRID_N = 1024;    // node_transform blocks
    const int GRID_E = 25000;   // edge_message blocks (4 waves each, 8 edges/wave)

    // ---- layer 1 ----
    node_transform<<<GRID_N, 256, 0, stream>>>(x, Wf1, Ws1, bf1, bs1, T);
    hipMemcpyAsync(h1, x, (size_t)N_NODES * D * sizeof(float),
                   hipMemcpyDeviceToDevice, stream);
    edge_message<<<GRID_E, 256, 0, stream>>>(T, ei, ea, Wf1, Ws1, h1);

    // ---- layer 2 ----
    node_transform<<<GRID_N, 256, 0, stream>>>(h1, Wf2, Ws2, bf2, bs2, T);
    hipMemcpyAsync(h2, h1, (size_t)N_NODES * D * sizeof(float),
                   hipMemcpyDeviceToDevice, stream);
    edge_message<<<GRID_E, 256, 0, stream>>>(T, ei, ea, Wf2, Ws2, h2);

    // ---- pool + out ----
    hipMemsetAsync(pooled, 0, (size_t)N_GRAPHS * D * sizeof(float), stream);
    pool_kernel<<<12500, 256, 0, stream>>>(h2, batch, pooled);
    out_kernel<<<2, 256, 0, stream>>>(pooled, Wout, bout, out);
}

// Round 6
// 724.847 us; speedup vs baseline: 1.2248x; 1.2248x over previous
//
#include <hip/hip_runtime.h>
#include <math.h>

#define N_NODES 50000
#define N_EDGES 800000
#define N_GRAPHS 512
#define D 64
#define DE 32

// ---------------------------------------------------------------------------
// R5 lesson: loop-invariant plain loads cannot be kept in VGPRs (compiler
// remats/sinks them; pinning spills). edge kernel was L1-bound on 64 weight
// reloads/edge (256 cy/edge ~= 333us, matching 346us measured).
// R6: MFMA everywhere. Weights become B-operand fragments (load+cvt+pack
// chains, non-rematerializable). bf16 inputs, fp32 accumulate/activations.
//
// NEW T layout per node n (256 floats), interleaved (f,s) pairs:
//   T[n*256 +   0 + 2j+0] = Af[n][j] = x[n] @ Wf[0:64]  + bf[j]  (dst, f)
//   T[n*256 +   0 + 2j+1] = As[n][j] = x[n] @ Ws[0:64]  + bs[j]  (dst, s)
//   T[n*256 + 128 + 2j+0] = Bf[n][j] = x[n] @ Wf[64:128]         (src, f)
//   T[n*256 + 128 + 2j+1] = Bs[n][j] = x[n] @ Ws[64:128]         (src, s)
// Edge epilogue reads one float2 per (dst,j) and one per (src,j).
//
// MFMA 16x16x32 bf16 fragment maps (m89/m120-verified):
//   A[m][k]: m = lane&15, k = (lane>>4)*8 + i   (i = elem 0..7)
//   B[k][n]: n = lane&15, k = (lane>>4)*8 + i
//   C/D    : col n = lane&15, row m = (lane>>4)*4 + reg
// ---------------------------------------------------------------------------

typedef __attribute__((ext_vector_type(8))) short short8;
typedef __attribute__((ext_vector_type(4))) float floatx4;

union Frag { short8 s; unsigned u[4]; };

// bf16 RNE convert + pack two floats -> one dword (lo | hi<<16)
__device__ inline unsigned pk_bf16(float lo, float hi) {
    unsigned a = __float_as_uint(lo);
    unsigned b = __float_as_uint(hi);
    a = (a + 0x7FFFu + ((a >> 16) & 1u)) >> 16;
    b = (b + 0x7FFFu + ((b >> 16) & 1u)) >> 16;
    return a | (b << 16);
}

// ---- node transform: T = [H @ (Wf|Ws parts)] in interleaved layout --------
// One wave per (16-node tile, 16-column block). 3125*16 = 50000 jobs.
__global__ __launch_bounds__(256) void node_transform_mfma(
    const float* __restrict__ H,          // [N_NODES][64]
    const float* __restrict__ Wf,         // [160][64]
    const float* __restrict__ Ws,         // [160][64]
    const float* __restrict__ bf,         // [64]
    const float* __restrict__ bs,         // [64]
    float* __restrict__ T)                // [N_NODES][256] interleaved
{
    const int lane = threadIdx.x & 63;
    const int wid  = threadIdx.x >> 6;
    const int n16  = lane & 15;
    const int quad = lane >> 4;
    const int kc   = quad * 8;

    const int NJOBS  = (N_NODES / 16) * 16;
    const int nwaves = gridDim.x * 4;
    for (int job = blockIdx.x * 4 + wid; job < NJOBS; job += nwaves) {
        const int ntile = job >> 4;
        const int cb    = job & 15;
        const int jj    = cb * 16 + n16;     // T column 0..255 (this lane)
        const int part  = jj >> 7;           // 0: dst-part, 1: src-part
        const int sflag = jj & 1;            // 0: f-matrix, 1: s-matrix
        const int j     = (jj >> 1) & 63;    // output channel
        const float* Wsel = sflag ? Ws : Wf;
        const int rbase = part * 64;         // W row base (x_i rows vs x_j rows)

        // B fragments for the two K-chunks (c = kc+i and c = 32+kc+i)
        Frag b0, b1;
        {
            float t0[8], t1[8];
#pragma unroll
            for (int i = 0; i < 8; ++i) {
                t0[i] = Wsel[(rbase + kc + i) * 64 + j];
                t1[i] = Wsel[(rbase + 32 + kc + i) * 64 + j];
            }
#pragma unroll
            for (int p = 0; p < 4; ++p) {
                b0.u[p] = pk_bf16(t0[2 * p], t0[2 * p + 1]);
                b1.u[p] = pk_bf16(t1[2 * p], t1[2 * p + 1]);
            }
        }
        float bias = 0.0f;
        if (part == 0) bias = sflag ? bs[j] : bf[j];

        // A fragments: node = ntile*16 + n16, features kc..kc+7 / 32+kc..+7
        const float* hrow = H + (size_t)(ntile * 16 + n16) * D;
        float4 q0 = *(const float4*)(hrow + kc);
        float4 q1 = *(const float4*)(hrow + kc + 4);
        float4 q2 = *(const float4*)(hrow + 32 + kc);
        float4 q3 = *(const float4*)(hrow + 32 + kc + 4);
        Frag a0, a1;
        a0.u[0] = pk_bf16(q0.x, q0.y); a0.u[1] = pk_bf16(q0.z, q0.w);
        a0.u[2] = pk_bf16(q1.x, q1.y); a0.u[3] = pk_bf16(q1.z, q1.w);
        a1.u[0] = pk_bf16(q2.x, q2.y); a1.u[1] = pk_bf16(q2.z, q2.w);
        a1.u[2] = pk_bf16(q3.x, q3.y); a1.u[3] = pk_bf16(q3.z, q3.w);

        floatx4 acc = {bias, bias, bias, bias};
        acc = __builtin_amdgcn_mfma_f32_16x16x32_bf16(a0.s, b0.s, acc, 0, 0, 0);
        acc = __builtin_amdgcn_mfma_f32_16x16x32_bf16(a1.s, b1.s, acc, 0, 0, 0);

#pragma unroll
        for (int r = 0; r < 4; ++r) {
            const int node = ntile * 16 + quad * 4 + r;
            T[(size_t)node * 256 + jj] = acc[r];
        }
    }
}

// ---- edge kernel: per 16-edge tile, msg_pre = ea @ We via MFMA, then
// epilogue adds T parts, activates, atomically aggregates into hout --------
__global__ __launch_bounds__(256) void edge_message_mfma(
    const float* __restrict__ T,          // [N_NODES][256] interleaved
    const int* __restrict__ ei,           // [2][N_EDGES]
    const float* __restrict__ ea,         // [N_EDGES][32]
    const float* __restrict__ Wf,         // [160][64] (rows 128..159 used)
    const float* __restrict__ Ws,
    float* __restrict__ hout)             // [N_NODES][64], pre-init to input h
{
    const int lane = threadIdx.x & 63;
    const int wid  = threadIdx.x >> 6;
    const int n16  = lane & 15;
    const int quad = lane >> 4;
    const int c0   = quad * 8;

    // B fragments: 4 j-blocks x {f,s}. k = c0+i, n = n16 -> j = jb*16+n16
    Frag bfr[4], bsr[4];
#pragma unroll
    for (int jb = 0; jb < 4; ++jb) {
        const int j = jb * 16 + n16;
        float tf[8], tsv[8];
#pragma unroll
        for (int i = 0; i < 8; ++i) {
            tf[i]  = Wf[(128 + c0 + i) * 64 + j];
            tsv[i] = Ws[(128 + c0 + i) * 64 + j];
        }
#pragma unroll
        for (int p = 0; p < 4; ++p) {
            bfr[jb].u[p] = pk_bf16(tf[2 * p], tf[2 * p + 1]);
            bsr[jb].u[p] = pk_bf16(tsv[2 * p], tsv[2 * p + 1]);
        }
    }

    const floatx4 zero = {0.0f, 0.0f, 0.0f, 0.0f};
    const int NT = N_EDGES / 16;
    const int nwaves = gridDim.x * 4;
    for (int t = blockIdx.x * 4 + wid; t < NT; t += nwaves) {
        const int e0 = t * 16;

        // A fragment: edge = e0 + n16 (m), k = c0 + i
        const float* arow = ea + (size_t)(e0 + n16) * DE + c0;
        float4 p0 = *(const float4*)(arow);
        float4 p1 = *(const float4*)(arow + 4);
        Frag af;
        af.u[0] = pk_bf16(p0.x, p0.y); af.u[1] = pk_bf16(p0.z, p0.w);
        af.u[2] = pk_bf16(p1.x, p1.y); af.u[3] = pk_bf16(p1.z, p1.w);

        floatx4 accf[4], accs[4];
#pragma unroll
        for (int jb = 0; jb < 4; ++jb) {
            accf[jb] = __builtin_amdgcn_mfma_f32_16x16x32_bf16(af.s, bfr[jb].s, zero, 0, 0, 0);
            accs[jb] = __builtin_amdgcn_mfma_f32_16x16x32_bf16(af.s, bsr[jb].s, zero, 0, 0, 0);
        }

        // epilogue: D row m = quad*4 + r -> edge, col n = n16 -> j = jb*16+n16
#pragma unroll
        for (int r = 0; r < 4; ++r) {
            const int e   = e0 + quad * 4 + r;
            const int src = ei[e];
            const int dst = ei[N_EDGES + e];
            const float* td = T + (size_t)dst * 256;        // (Af,As) pairs
            const float* ts = T + (size_t)src * 256 + 128;  // (Bf,Bs) pairs
            float* hrow = hout + (size_t)dst * D;
#pragma unroll
            for (int jb = 0; jb < 4; ++jb) {
                const int j = jb * 16 + n16;
                float2 dp = *(const float2*)(td + 2 * j);
                float2 sp2 = *(const float2*)(ts + 2 * j);
                float vf = accf[jb][r] + dp.x + sp2.x;
                float vs = accs[jb][r] + dp.y + sp2.y;
                float sig = 1.0f / (1.0f + __expf(-vf));
                float spl = fmaxf(vs, 0.0f) + log1pf(__expf(-fabsf(vs)));
                atomicAdd(hrow + j, sig * spl);
            }
        }
    }
}

// segment_sum(h, batch) into pooled[N_GRAPHS][64]
__global__ __launch_bounds__(256) void pool_kernel(
    const float* __restrict__ h,          // [N_NODES][64]
    const int* __restrict__ batch,        // [N_NODES]
    float* __restrict__ pooled)           // [N_GRAPHS][64], pre-zeroed
{
    const int lane = threadIdx.x & 63;
    const int wid  = threadIdx.x >> 6;
    const int nwaves = gridDim.x * 4;
    for (int n = blockIdx.x * 4 + wid; n < N_NODES; n += nwaves) {
        const int g = batch[n];
        atomicAdd(&pooled[(size_t)g * D + lane], h[(size_t)n * D + lane]);
    }
}

__global__ __launch_bounds__(256) void out_kernel(
    const float* __restrict__ pooled,     // [N_GRAPHS][64]
    const float* __restrict__ Wout,       // [64]
    const float* __restrict__ bout,       // [1]
    float* __restrict__ out)              // [N_GRAPHS]
{
    const int g = blockIdx.x * blockDim.x + threadIdx.x;
    if (g >= N_GRAPHS) return;
    float acc = bout[0];
#pragma unroll
    for (int j = 0; j < D; ++j) acc = fmaf(pooled[(size_t)g * D + j], Wout[j], acc);
    out[g] = acc;
}

extern "C" void kernel_launch(void* const* d_in, const int* in_sizes, int n_in,
                              void* d_out, int out_size, void* d_ws, size_t ws_size,
                              hipStream_t stream) {
    const float* x     = (const float*)d_in[0];
    const int*   ei    = (const int*)  d_in[1];
    const float* ea    = (const float*)d_in[2];
    const int*   batch = (const int*)  d_in[3];
    const float* Wf1   = (const float*)d_in[4];
    const float* bf1   = (const float*)d_in[5];
    const float* Ws1   = (const float*)d_in[6];
    const float* bs1   = (const float*)d_in[7];
    const float* Wf2   = (const float*)d_in[8];
    const float* bf2   = (const float*)d_in[9];
    const float* Ws2   = (const float*)d_in[10];
    const float* bs2   = (const float*)d_in[11];
    const float* Wout  = (const float*)d_in[12];
    const float* bout  = (const float*)d_in[13];
    float* out = (float*)d_out;

    // workspace layout
    float* T      = (float*)d_ws;                       // 50000*256
    float* h1     = T + (size_t)N_NODES * 256;          // 50000*64
    float* h2     = h1 + (size_t)N_NODES * D;           // 50000*64
    float* pooled = h2 + (size_t)N_NODES * D;           // 512*64

    const int GRID_N = 3125;   // node_transform_mfma: 12500 waves, 4 jobs each
    const int GRID_E = 3125;   // edge_message_mfma:  12500 waves, 4 tiles each

    // ---- layer 1 ----
    node_transform_mfma<<<GRID_N, 256, 0, stream>>>(x, Wf1, Ws1, bf1, bs1, T);
    hipMemcpyAsync(h1, x, (size_t)N_NODES * D * sizeof(float),
                   hipMemcpyDeviceToDevice, stream);
    edge_message_mfma<<<GRID_E, 256, 0, stream>>>(T, ei, ea, Wf1, Ws1, h1);

    // ---- layer 2 ----
    node_transform_mfma<<<GRID_N, 256, 0, stream>>>(h1, Wf2, Ws2, bf2, bs2, T);
    hipMemcpyAsync(h2, h1, (size_t)N_NODES * D * sizeof(float),
                   hipMemcpyDeviceToDevice, stream);
    edge_message_mfma<<<GRID_E, 256, 0, stream>>>(T, ei, ea, Wf2, Ws2, h2);

    // ---- pool + out ----
    hipMemsetAsync(pooled, 0, (size_t)N_GRAPHS * D * sizeof(float), stream);
    pool_kernel<<<12500, 256, 0, stream>>>(h2, batch, pooled);
    out_kernel<<<2, 256, 0, stream>>>(pooled, Wout, bout, out);
}

// Round 7
// 643.045 us; speedup vs baseline: 1.3806x; 1.1272x over previous
//
#include <hip/hip_runtime.h>
#include <math.h>

#define N_NODES 50000
#define N_EDGES 800000
#define N_GRAPHS 512
#define D 64
#define DE 32
#define NTILE (N_EDGES / 16)   // 50000 16-edge tiles
#define NB_SCAN 196            // ceil(50000/256)

// ---------------------------------------------------------------------------
// R6 lesson: MFMA fixed the weight-reload disease (847->725us), but the edge
// kernel is bound by 51.2M fp32 atomic RMWs + 1KB/edge random T-gather.
// R7: counting-sort edges by dst once per call (CSR). Edge kernel walks the
// sorted order (dst ~constant per tile -> td cache-hot), writes post-
// activation messages as bf16 to contiguous P (plain stores). A streaming
// aggregate kernel sums P rows per dst -> h. Zero atomics in the h path.
// T is bf16 interleaved (f,s) pairs: T16[n*256 + 2j+{0,1}] = dst-part f/s,
// T16[n*256 + 128 + 2j+{0,1}] = src-part f/s.
//
// MFMA 16x16x32 bf16 fragment maps (m89/m120-verified):
//   A[m][k]: m = lane&15, k = (lane>>4)*8 + i
//   B[k][n]: n = lane&15, k = (lane>>4)*8 + i
//   C/D    : col n = lane&15, row m = (lane>>4)*4 + reg
// ---------------------------------------------------------------------------

typedef __attribute__((ext_vector_type(8))) short short8;
typedef __attribute__((ext_vector_type(4))) float floatx4;
union Frag { short8 s; unsigned u[4]; };

// bf16 RNE: pack two floats -> dword
__device__ inline unsigned pk_bf16(float lo, float hi) {
    unsigned a = __float_as_uint(lo);
    unsigned b = __float_as_uint(hi);
    a = (a + 0x7FFFu + ((a >> 16) & 1u)) >> 16;
    b = (b + 0x7FFFu + ((b >> 16) & 1u)) >> 16;
    return a | (b << 16);
}
__device__ inline unsigned short bf16_1(float v) {
    unsigned a = __float_as_uint(v);
    return (unsigned short)((a + 0x7FFFu + ((a >> 16) & 1u)) >> 16);
}
__device__ inline float upk(unsigned u16) {  // low 16 bits = bf16
    return __uint_as_float(u16 << 16);
}

// ---------------- CSR build (once per call, reused by both layers) --------
__global__ __launch_bounds__(256) void hist_kernel(
    const int* __restrict__ ei, int* __restrict__ deg)
{
    int e = blockIdx.x * 256 + threadIdx.x;
    atomicAdd(&deg[ei[N_EDGES + e]], 1);
}

__global__ __launch_bounds__(256) void scan1(
    const int* __restrict__ deg, int* __restrict__ off, int* __restrict__ tsum)
{
    __shared__ int s[256];
    int i = blockIdx.x * 256 + threadIdx.x;
    s[threadIdx.x] = (i < N_NODES) ? deg[i] : 0;
    __syncthreads();
    if (threadIdx.x == 0) {
        int run = 0;
        for (int k = 0; k < 256; ++k) { int t = s[k]; s[k] = run; run += t; }
        tsum[blockIdx.x] = run;
    }
    __syncthreads();
    if (i < N_NODES) off[i] = s[threadIdx.x];
}

__global__ __launch_bounds__(256) void scan2(int* __restrict__ tsum)
{
    __shared__ int s[256];
    int i = threadIdx.x;
    s[i] = (i < NB_SCAN) ? tsum[i] : 0;
    __syncthreads();
    if (i == 0) {
        int run = 0;
        for (int k = 0; k < NB_SCAN; ++k) { int t = s[k]; s[k] = run; run += t; }
    }
    __syncthreads();
    if (i < NB_SCAN) tsum[i] = s[i];
}

__global__ __launch_bounds__(256) void scan3(
    int* __restrict__ off, const int* __restrict__ tsum)
{
    int i = blockIdx.x * 256 + threadIdx.x;
    if (i < N_NODES) off[i] += tsum[blockIdx.x];
    if (i == N_NODES) off[i] = N_EDGES;
}

__global__ __launch_bounds__(256) void scatter_kernel(
    const int* __restrict__ ei, const int* __restrict__ off,
    int* __restrict__ cnt, int* __restrict__ perm)
{
    int e = blockIdx.x * 256 + threadIdx.x;
    int d = ei[N_EDGES + e];
    int r = atomicAdd(&cnt[d], 1);
    perm[off[d] + r] = e;
}

// ---- node transform: T16 = bf16[H @ W parts], interleaved layout ----------
__global__ __launch_bounds__(256) void node_transform_mfma(
    const float* __restrict__ H,          // [N_NODES][64]
    const float* __restrict__ Wf,         // [160][64]
    const float* __restrict__ Ws,         // [160][64]
    const float* __restrict__ bf,         // [64]
    const float* __restrict__ bs,         // [64]
    unsigned short* __restrict__ T16)     // [N_NODES][256] bf16 interleaved
{
    const int lane = threadIdx.x & 63;
    const int wid  = threadIdx.x >> 6;
    const int n16  = lane & 15;
    const int quad = lane >> 4;
    const int kc   = quad * 8;

    const int NJOBS  = (N_NODES / 16) * 16;
    const int nwaves = gridDim.x * 4;
    for (int job = blockIdx.x * 4 + wid; job < NJOBS; job += nwaves) {
        const int ntile = job >> 4;
        const int cb    = job & 15;
        const int jj    = cb * 16 + n16;     // T column 0..255
        const int part  = jj >> 7;           // 0: dst-part, 1: src-part
        const int sflag = jj & 1;            // 0: f, 1: s
        const int j     = (jj >> 1) & 63;
        const float* Wsel = sflag ? Ws : Wf;
        const int rbase = part * 64;

        Frag b0, b1;
        {
            float t0[8], t1[8];
#pragma unroll
            for (int i = 0; i < 8; ++i) {
                t0[i] = Wsel[(rbase + kc + i) * 64 + j];
                t1[i] = Wsel[(rbase + 32 + kc + i) * 64 + j];
            }
#pragma unroll
            for (int p = 0; p < 4; ++p) {
                b0.u[p] = pk_bf16(t0[2 * p], t0[2 * p + 1]);
                b1.u[p] = pk_bf16(t1[2 * p], t1[2 * p + 1]);
            }
        }
        float bias = 0.0f;
        if (part == 0) bias = sflag ? bs[j] : bf[j];

        const float* hrow = H + (size_t)(ntile * 16 + n16) * D;
        float4 q0 = *(const float4*)(hrow + kc);
        float4 q1 = *(const float4*)(hrow + kc + 4);
        float4 q2 = *(const float4*)(hrow + 32 + kc);
        float4 q3 = *(const float4*)(hrow + 32 + kc + 4);
        Frag a0, a1;
        a0.u[0] = pk_bf16(q0.x, q0.y); a0.u[1] = pk_bf16(q0.z, q0.w);
        a0.u[2] = pk_bf16(q1.x, q1.y); a0.u[3] = pk_bf16(q1.z, q1.w);
        a1.u[0] = pk_bf16(q2.x, q2.y); a1.u[1] = pk_bf16(q2.z, q2.w);
        a1.u[2] = pk_bf16(q3.x, q3.y); a1.u[3] = pk_bf16(q3.z, q3.w);

        floatx4 acc = {bias, bias, bias, bias};
        acc = __builtin_amdgcn_mfma_f32_16x16x32_bf16(a0.s, b0.s, acc, 0, 0, 0);
        acc = __builtin_amdgcn_mfma_f32_16x16x32_bf16(a1.s, b1.s, acc, 0, 0, 0);

#pragma unroll
        for (int r = 0; r < 4; ++r) {
            const int node = ntile * 16 + quad * 4 + r;
            T16[(size_t)node * 256 + jj] = bf16_1(acc[r]);
        }
    }
}

// ---- edge kernel: sorted order; MFMA ea@We; activation; bf16 store to P --
__global__ __launch_bounds__(256) void edge_message_mfma(
    const unsigned short* __restrict__ T16,  // [N_NODES][256] bf16
    const int* __restrict__ ei,              // [2][N_EDGES]
    const float* __restrict__ ea,            // [N_EDGES][32]
    const int* __restrict__ perm,            // [N_EDGES] sorted-by-dst
    const float* __restrict__ Wf,            // rows 128..159 used
    const float* __restrict__ Ws,
    unsigned short* __restrict__ P)          // [N_EDGES][64] bf16 messages
{
    const int lane = threadIdx.x & 63;
    const int wid  = threadIdx.x >> 6;
    const int n16  = lane & 15;
    const int quad = lane >> 4;
    const int c0   = quad * 8;

    Frag bfr[4], bsr[4];
#pragma unroll
    for (int jb = 0; jb < 4; ++jb) {
        const int j = jb * 16 + n16;
        float tf[8], tsv[8];
#pragma unroll
        for (int i = 0; i < 8; ++i) {
            tf[i]  = Wf[(128 + c0 + i) * 64 + j];
            tsv[i] = Ws[(128 + c0 + i) * 64 + j];
        }
#pragma unroll
        for (int p = 0; p < 4; ++p) {
            bfr[jb].u[p] = pk_bf16(tf[2 * p], tf[2 * p + 1]);
            bsr[jb].u[p] = pk_bf16(tsv[2 * p], tsv[2 * p + 1]);
        }
    }

    const floatx4 zero = {0.0f, 0.0f, 0.0f, 0.0f};
    const int nwaves = gridDim.x * 4;
    for (int t = blockIdx.x * 4 + wid; t < NTILE; t += nwaves) {
        const int p0 = t * 16;

        // A fragment: sorted position p0+n16 -> edge perm[...], row gather
        const int erow = perm[p0 + n16];
        const float* arow = ea + (size_t)erow * DE + c0;
        float4 q0 = *(const float4*)(arow);
        float4 q1 = *(const float4*)(arow + 4);
        Frag af;
        af.u[0] = pk_bf16(q0.x, q0.y); af.u[1] = pk_bf16(q0.z, q0.w);
        af.u[2] = pk_bf16(q1.x, q1.y); af.u[3] = pk_bf16(q1.z, q1.w);

        floatx4 accf[4], accs[4];
#pragma unroll
        for (int jb = 0; jb < 4; ++jb) {
            accf[jb] = __builtin_amdgcn_mfma_f32_16x16x32_bf16(af.s, bfr[jb].s, zero, 0, 0, 0);
            accs[jb] = __builtin_amdgcn_mfma_f32_16x16x32_bf16(af.s, bsr[jb].s, zero, 0, 0, 0);
        }

#pragma unroll
        for (int r = 0; r < 4; ++r) {
            const int pp  = p0 + quad * 4 + r;
            const int e   = perm[pp];             // quad-uniform broadcast
            const int src = ei[e];
            const int dst = ei[N_EDGES + e];      // ~constant per tile: L1-hot
            const unsigned short* td = T16 + (size_t)dst * 256;
            const unsigned short* ts = T16 + (size_t)src * 256 + 128;
            unsigned short* prow = P + (size_t)pp * 64;
#pragma unroll
            for (int jb = 0; jb < 4; ++jb) {
                const int j = jb * 16 + n16;
                unsigned d2 = *(const unsigned*)(td + 2 * j);  // (f,s) pair
                unsigned s2 = *(const unsigned*)(ts + 2 * j);
                float vf = accf[jb][r] + upk(d2 & 0xFFFFu) + upk(s2 & 0xFFFFu);
                float vs = accs[jb][r] + upk(d2 >> 16) + upk(s2 >> 16);
                float sig = __builtin_amdgcn_rcpf(1.0f + __expf(-vf));
                float spl = fmaxf(vs, 0.0f) + __logf(1.0f + __expf(-fabsf(vs)));
                prow[j] = bf16_1(sig * spl);
            }
        }
    }
}

// ---- streaming aggregation: h[n] = hin[n] + sum of P rows [off[n],off[n+1])
__global__ __launch_bounds__(256) void aggregate(
    const unsigned short* __restrict__ P,
    const int* __restrict__ off,
    const float* __restrict__ hin,
    float* __restrict__ hout)
{
    const int lane = threadIdx.x & 63;
    const int wid  = threadIdx.x >> 6;
    const int n = blockIdx.x * 4 + wid;
    if (n >= N_NODES) return;
    const int b = off[n], e = off[n + 1];
    float acc = hin[(size_t)n * D + lane];
    int p = b;
    for (; p + 1 < e; p += 2) {
        float v0 = upk((unsigned)P[(size_t)p * 64 + lane]);
        float v1 = upk((unsigned)P[(size_t)(p + 1) * 64 + lane]);
        acc += v0 + v1;
    }
    if (p < e) acc += upk((unsigned)P[(size_t)p * 64 + lane]);
    hout[(size_t)n * D + lane] = acc;
}

// segment_sum(h, batch) into pooled[N_GRAPHS][64]
__global__ __launch_bounds__(256) void pool_kernel(
    const float* __restrict__ h,
    const int* __restrict__ batch,
    float* __restrict__ pooled)
{
    const int lane = threadIdx.x & 63;
    const int wid  = threadIdx.x >> 6;
    const int n = blockIdx.x * 4 + wid;
    if (n >= N_NODES) return;
    atomicAdd(&pooled[(size_t)batch[n] * D + lane], h[(size_t)n * D + lane]);
}

__global__ __launch_bounds__(256) void out_kernel(
    const float* __restrict__ pooled,
    const float* __restrict__ Wout,
    const float* __restrict__ bout,
    float* __restrict__ out)
{
    const int g = blockIdx.x * blockDim.x + threadIdx.x;
    if (g >= N_GRAPHS) return;
    float acc = bout[0];
#pragma unroll
    for (int j = 0; j < D; ++j) acc = fmaf(pooled[(size_t)g * D + j], Wout[j], acc);
    out[g] = acc;
}

extern "C" void kernel_launch(void* const* d_in, const int* in_sizes, int n_in,
                              void* d_out, int out_size, void* d_ws, size_t ws_size,
                              hipStream_t stream) {
    const float* x     = (const float*)d_in[0];
    const int*   ei    = (const int*)  d_in[1];
    const float* ea    = (const float*)d_in[2];
    const int*   batch = (const int*)  d_in[3];
    const float* Wf1   = (const float*)d_in[4];
    const float* bf1   = (const float*)d_in[5];
    const float* Ws1   = (const float*)d_in[6];
    const float* bs1   = (const float*)d_in[7];
    const float* Wf2   = (const float*)d_in[8];
    const float* bf2   = (const float*)d_in[9];
    const float* Ws2   = (const float*)d_in[10];
    const float* bs2   = (const float*)d_in[11];
    const float* Wout  = (const float*)d_in[12];
    const float* bout  = (const float*)d_in[13];
    float* out = (float*)d_out;

    // workspace carve (≈157.4 MB total)
    char* base = (char*)d_ws;
    size_t o = 0;
    unsigned short* T16 = (unsigned short*)(base + o); o += (size_t)N_NODES * 256 * 2;  // 25.6 MB
    unsigned short* P   = (unsigned short*)(base + o); o += (size_t)N_EDGES * 64 * 2;   // 102.4 MB
    float* h1     = (float*)(base + o); o += (size_t)N_NODES * D * 4;                   // 12.8 MB
    float* h2     = (float*)(base + o); o += (size_t)N_NODES * D * 4;                   // 12.8 MB
    float* pooled = (float*)(base + o); o += (size_t)N_GRAPHS * D * 4;
    int* deg  = (int*)(base + o); o += (size_t)N_NODES * 4;
    int* off  = (int*)(base + o); o += (size_t)(N_NODES + 1) * 4;
    int* tsum = (int*)(base + o); o += 256 * 4;
    int* perm = (int*)(base + o); o += (size_t)N_EDGES * 4;

    // ---- CSR build (dst-sorted edge permutation), reused by both layers ----
    hipMemsetAsync(deg, 0, (size_t)N_NODES * 4, stream);
    hist_kernel<<<N_EDGES / 256, 256, 0, stream>>>(ei, deg);
    scan1<<<NB_SCAN, 256, 0, stream>>>(deg, off, tsum);
    scan2<<<1, 256, 0, stream>>>(tsum);
    scan3<<<NB_SCAN, 256, 0, stream>>>(off, tsum);
    hipMemsetAsync(deg, 0, (size_t)N_NODES * 4, stream);
    scatter_kernel<<<N_EDGES / 256, 256, 0, stream>>>(ei, off, deg, perm);

    // ---- layer 1 ----
    node_transform_mfma<<<3125, 256, 0, stream>>>(x, Wf1, Ws1, bf1, bs1, T16);
    edge_message_mfma<<<3125, 256, 0, stream>>>(T16, ei, ea, perm, Wf1, Ws1, P);
    aggregate<<<12500, 256, 0, stream>>>(P, off, x, h1);

    // ---- layer 2 ----
    node_transform_mfma<<<3125, 256, 0, stream>>>(h1, Wf2, Ws2, bf2, bs2, T16);
    edge_message_mfma<<<3125, 256, 0, stream>>>(T16, ei, ea, perm, Wf2, Ws2, P);
    aggregate<<<12500, 256, 0, stream>>>(P, off, h1, h2);

    // ---- pool + out ----
    hipMemsetAsync(pooled, 0, (size_t)N_GRAPHS * D * 4, stream);
    pool_kernel<<<12500, 256, 0, stream>>>(h2, batch, pooled);
    out_kernel<<<2, 256, 0, stream>>>(pooled, Wout, bout, out);
}

// Round 8
// 551.483 us; speedup vs baseline: 1.6098x; 1.1660x over previous
//
#include <hip/hip_runtime.h>
#include <math.h>

#define N_NODES 50000
#define N_EDGES 800000
#define N_GRAPHS 512
#define D 64
#define DE 32
#define NTILE (N_EDGES / 16)   // 50000 16-edge tiles
#define NB_SCAN 196            // ceil(50000/256)
#define LSTR 68                // LDS row stride (floats), bank-spread

// ---------------------------------------------------------------------------
// R7 lesson: P message buffer round-trip (102MB write + read) + 2 extra
// dispatches ate the CSR win. R8: fuse aggregation into the edge kernel.
// Edges are dst-sorted -> per 16-edge tile ~2-3 dst runs; write activated
// messages to wave-private LDS, segmented-scan rows, one 64-lane atomicAdd
// per run. scatter also emits src_sorted/dst_sorted (no ei gathers in edge
// kernel). T split: Tdst[n][128], Tsrc[n][128] bf16 interleaved (f,s) pairs.
//
// MFMA 16x16x32 bf16 fragment maps (m89/m120-verified):
//   A[m][k]: m = lane&15, k = (lane>>4)*8 + i
//   B[k][n]: n = lane&15, k = (lane>>4)*8 + i
//   C/D    : col n = lane&15, row m = (lane>>4)*4 + reg
// ---------------------------------------------------------------------------

typedef __attribute__((ext_vector_type(8))) short short8;
typedef __attribute__((ext_vector_type(4))) float floatx4;
union Frag { short8 s; unsigned u[4]; };

__device__ inline unsigned pk_bf16(float lo, float hi) {
    unsigned a = __float_as_uint(lo);
    unsigned b = __float_as_uint(hi);
    a = (a + 0x7FFFu + ((a >> 16) & 1u)) >> 16;
    b = (b + 0x7FFFu + ((b >> 16) & 1u)) >> 16;
    return a | (b << 16);
}
__device__ inline unsigned short bf16_1(float v) {
    unsigned a = __float_as_uint(v);
    return (unsigned short)((a + 0x7FFFu + ((a >> 16) & 1u)) >> 16);
}
__device__ inline float upk(unsigned u16) { return __uint_as_float(u16 << 16); }

// ---------------- CSR build (once per call) --------------------------------
__global__ __launch_bounds__(256) void hist_kernel(
    const int* __restrict__ ei, int* __restrict__ deg)
{
    int e = blockIdx.x * 256 + threadIdx.x;
    atomicAdd(&deg[ei[N_EDGES + e]], 1);
}

__global__ __launch_bounds__(256) void scan1(
    const int* __restrict__ deg, int* __restrict__ off, int* __restrict__ tsum)
{
    __shared__ int s[256];
    int i = blockIdx.x * 256 + threadIdx.x;
    s[threadIdx.x] = (i < N_NODES) ? deg[i] : 0;
    __syncthreads();
    if (threadIdx.x == 0) {
        int run = 0;
        for (int k = 0; k < 256; ++k) { int t = s[k]; s[k] = run; run += t; }
        tsum[blockIdx.x] = run;
    }
    __syncthreads();
    if (i < N_NODES) off[i] = s[threadIdx.x];
}

__global__ __launch_bounds__(256) void scan2(int* __restrict__ tsum)
{
    __shared__ int s[256];
    int i = threadIdx.x;
    s[i] = (i < NB_SCAN) ? tsum[i] : 0;
    __syncthreads();
    if (i == 0) {
        int run = 0;
        for (int k = 0; k < NB_SCAN; ++k) { int t = s[k]; s[k] = run; run += t; }
    }
    __syncthreads();
    if (i < NB_SCAN) tsum[i] = s[i];
}

__global__ __launch_bounds__(256) void scan3(
    int* __restrict__ off, const int* __restrict__ tsum)
{
    int i = blockIdx.x * 256 + threadIdx.x;
    if (i < N_NODES) off[i] += tsum[blockIdx.x];
    if (i == N_NODES) off[i] = N_EDGES;
}

__global__ __launch_bounds__(256) void scatter_kernel(
    const int* __restrict__ ei, const int* __restrict__ off,
    int* __restrict__ cnt, int* __restrict__ perm,
    int* __restrict__ src_sorted, int* __restrict__ dst_sorted)
{
    int e = blockIdx.x * 256 + threadIdx.x;
    int s = ei[e];
    int d = ei[N_EDGES + e];
    int r = atomicAdd(&cnt[d], 1);
    int pos = off[d] + r;
    perm[pos] = e;
    src_sorted[pos] = s;
    dst_sorted[pos] = d;
}

// ---- node transform: Tdst/Tsrc = bf16[H @ W parts], (f,s)-pair layout -----
__global__ __launch_bounds__(256) void node_transform_mfma(
    const float* __restrict__ H,
    const float* __restrict__ Wf,
    const float* __restrict__ Ws,
    const float* __restrict__ bf,
    const float* __restrict__ bs,
    unsigned short* __restrict__ Tdst,    // [N_NODES][128]
    unsigned short* __restrict__ Tsrc)    // [N_NODES][128]
{
    const int lane = threadIdx.x & 63;
    const int wid  = threadIdx.x >> 6;
    const int n16  = lane & 15;
    const int quad = lane >> 4;
    const int kc   = quad * 8;

    const int NJOBS  = (N_NODES / 16) * 16;
    const int nwaves = gridDim.x * 4;
    for (int job = blockIdx.x * 4 + wid; job < NJOBS; job += nwaves) {
        const int ntile = job >> 4;
        const int cb    = job & 15;
        const int jj    = cb * 16 + n16;     // 0..255
        const int part  = jj >> 7;           // 0: dst-part, 1: src-part
        const int col   = jj & 127;
        const int sflag = jj & 1;
        const int j     = (jj >> 1) & 63;
        const float* Wsel = sflag ? Ws : Wf;
        const int rbase = part * 64;
        unsigned short* Tout = part ? Tsrc : Tdst;

        Frag b0, b1;
        {
            float t0[8], t1[8];
#pragma unroll
            for (int i = 0; i < 8; ++i) {
                t0[i] = Wsel[(rbase + kc + i) * 64 + j];
                t1[i] = Wsel[(rbase + 32 + kc + i) * 64 + j];
            }
#pragma unroll
            for (int p = 0; p < 4; ++p) {
                b0.u[p] = pk_bf16(t0[2 * p], t0[2 * p + 1]);
                b1.u[p] = pk_bf16(t1[2 * p], t1[2 * p + 1]);
            }
        }
        float bias = 0.0f;
        if (part == 0) bias = sflag ? bs[j] : bf[j];

        const float* hrow = H + (size_t)(ntile * 16 + n16) * D;
        float4 q0 = *(const float4*)(hrow + kc);
        float4 q1 = *(const float4*)(hrow + kc + 4);
        float4 q2 = *(const float4*)(hrow + 32 + kc);
        float4 q3 = *(const float4*)(hrow + 32 + kc + 4);
        Frag a0, a1;
        a0.u[0] = pk_bf16(q0.x, q0.y); a0.u[1] = pk_bf16(q0.z, q0.w);
        a0.u[2] = pk_bf16(q1.x, q1.y); a0.u[3] = pk_bf16(q1.z, q1.w);
        a1.u[0] = pk_bf16(q2.x, q2.y); a1.u[1] = pk_bf16(q2.z, q2.w);
        a1.u[2] = pk_bf16(q3.x, q3.y); a1.u[3] = pk_bf16(q3.z, q3.w);

        floatx4 acc = {bias, bias, bias, bias};
        acc = __builtin_amdgcn_mfma_f32_16x16x32_bf16(a0.s, b0.s, acc, 0, 0, 0);
        acc = __builtin_amdgcn_mfma_f32_16x16x32_bf16(a1.s, b1.s, acc, 0, 0, 0);

#pragma unroll
        for (int r = 0; r < 4; ++r) {
            const int node = ntile * 16 + quad * 4 + r;
            Tout[(size_t)node * 128 + col] = bf16_1(acc[r]);
        }
    }
}

// ---- edge kernel with fused segmented aggregation -------------------------
__global__ __launch_bounds__(256) void edge_message_mfma(
    const unsigned short* __restrict__ Tdst,  // [N_NODES][128] bf16
    const unsigned short* __restrict__ Tsrc,  // [N_NODES][128] bf16
    const float* __restrict__ ea,             // [N_EDGES][32]
    const int* __restrict__ perm,             // [N_EDGES]
    const int* __restrict__ src_sorted,       // [N_EDGES]
    const int* __restrict__ dst_sorted,       // [N_EDGES] non-decreasing
    const float* __restrict__ Wf,             // rows 128..159 used
    const float* __restrict__ Ws,
    float* __restrict__ hout)                 // [N_NODES][64], pre-init = hin
{
    __shared__ float lds[4][16 * LSTR];
    const int lane = threadIdx.x & 63;
    const int wid  = threadIdx.x >> 6;
    const int n16  = lane & 15;
    const int quad = lane >> 4;
    const int c0   = quad * 8;
    float* L = lds[wid];

    Frag bfr[4], bsr[4];
#pragma unroll
    for (int jb = 0; jb < 4; ++jb) {
        const int j = jb * 16 + n16;
        float tf[8], tsv[8];
#pragma unroll
        for (int i = 0; i < 8; ++i) {
            tf[i]  = Wf[(128 + c0 + i) * 64 + j];
            tsv[i] = Ws[(128 + c0 + i) * 64 + j];
        }
#pragma unroll
        for (int p = 0; p < 4; ++p) {
            bfr[jb].u[p] = pk_bf16(tf[2 * p], tf[2 * p + 1]);
            bsr[jb].u[p] = pk_bf16(tsv[2 * p], tsv[2 * p + 1]);
        }
    }

    const floatx4 zero = {0.0f, 0.0f, 0.0f, 0.0f};
    const int nwaves = gridDim.x * 4;
    for (int t = blockIdx.x * 4 + wid; t < NTILE; t += nwaves) {
        const int p0 = t * 16;

        // per-tile metadata: lanes 0..15 meaningful (others mirror)
        const int sv16 = src_sorted[p0 + n16];
        const int dv16 = dst_sorted[p0 + n16];

        // A fragment: sorted position p0+n16 -> edge perm[...]
        const int erow = perm[p0 + n16];
        const float* arow = ea + (size_t)erow * DE + c0;
        float4 q0 = *(const float4*)(arow);
        float4 q1 = *(const float4*)(arow + 4);
        Frag af;
        af.u[0] = pk_bf16(q0.x, q0.y); af.u[1] = pk_bf16(q0.z, q0.w);
        af.u[2] = pk_bf16(q1.x, q1.y); af.u[3] = pk_bf16(q1.z, q1.w);

        floatx4 accf[4], accs[4];
#pragma unroll
        for (int jb = 0; jb < 4; ++jb) {
            accf[jb] = __builtin_amdgcn_mfma_f32_16x16x32_bf16(af.s, bfr[jb].s, zero, 0, 0, 0);
            accs[jb] = __builtin_amdgcn_mfma_f32_16x16x32_bf16(af.s, bsr[jb].s, zero, 0, 0, 0);
        }

        // activation + write message rows into wave-private LDS
#pragma unroll
        for (int r = 0; r < 4; ++r) {
            const int m = quad * 4 + r;               // row (sorted pos p0+m)
            const int sv = __shfl(sv16, m);           // src of row m
            const int dv = __shfl(dv16, m);           // dst of row m
            const unsigned short* td = Tdst + (size_t)dv * 128;
            const unsigned short* ts = Tsrc + (size_t)sv * 128;
#pragma unroll
            for (int jb = 0; jb < 4; ++jb) {
                const int j = jb * 16 + n16;
                unsigned d2 = *(const unsigned*)(td + 2 * j);
                unsigned s2 = *(const unsigned*)(ts + 2 * j);
                float vf = accf[jb][r] + upk(d2 & 0xFFFFu) + upk(s2 & 0xFFFFu);
                float vs = accs[jb][r] + upk(d2 >> 16) + upk(s2 >> 16);
                float sig = __builtin_amdgcn_rcpf(1.0f + __expf(-vf));
                float spl = fmaxf(vs, 0.0f) + __logf(1.0f + __expf(-fabsf(vs)));
                L[m * LSTR + j] = sig * spl;
            }
        }

        // segmented scan over the 16 rows (dst runs), lane = channel
        {
            int cur = __builtin_amdgcn_readlane(dv16, 0);
            float acc = L[0 * LSTR + lane];
#pragma unroll
            for (int r = 1; r < 16; ++r) {
                int d = __builtin_amdgcn_readlane(dv16, r);
                float v = L[r * LSTR + lane];
                if (d != cur) {
                    atomicAdd(&hout[(size_t)cur * D + lane], acc);
                    cur = d; acc = v;
                } else {
                    acc += v;
                }
            }
            atomicAdd(&hout[(size_t)cur * D + lane], acc);
        }
    }
}

// segment_sum(h, batch) into pooled[N_GRAPHS][64]
__global__ __launch_bounds__(256) void pool_kernel(
    const float* __restrict__ h,
    const int* __restrict__ batch,
    float* __restrict__ pooled)
{
    const int lane = threadIdx.x & 63;
    const int wid  = threadIdx.x >> 6;
    const int n = blockIdx.x * 4 + wid;
    if (n >= N_NODES) return;
    atomicAdd(&pooled[(size_t)batch[n] * D + lane], h[(size_t)n * D + lane]);
}

__global__ __launch_bounds__(256) void out_kernel(
    const float* __restrict__ pooled,
    const float* __restrict__ Wout,
    const float* __restrict__ bout,
    float* __restrict__ out)
{
    const int g = blockIdx.x * blockDim.x + threadIdx.x;
    if (g >= N_GRAPHS) return;
    float acc = bout[0];
#pragma unroll
    for (int j = 0; j < D; ++j) acc = fmaf(pooled[(size_t)g * D + j], Wout[j], acc);
    out[g] = acc;
}

extern "C" void kernel_launch(void* const* d_in, const int* in_sizes, int n_in,
                              void* d_out, int out_size, void* d_ws, size_t ws_size,
                              hipStream_t stream) {
    const float* x     = (const float*)d_in[0];
    const int*   ei    = (const int*)  d_in[1];
    const float* ea    = (const float*)d_in[2];
    const int*   batch = (const int*)  d_in[3];
    const float* Wf1   = (const float*)d_in[4];
    const float* bf1   = (const float*)d_in[5];
    const float* Ws1   = (const float*)d_in[6];
    const float* bs1   = (const float*)d_in[7];
    const float* Wf2   = (const float*)d_in[8];
    const float* bf2   = (const float*)d_in[9];
    const float* Ws2   = (const float*)d_in[10];
    const float* bs2   = (const float*)d_in[11];
    const float* Wout  = (const float*)d_in[12];
    const float* bout  = (const float*)d_in[13];
    float* out = (float*)d_out;

    // workspace carve (~64 MB)
    char* base = (char*)d_ws;
    size_t o = 0;
    unsigned short* Tdst = (unsigned short*)(base + o); o += (size_t)N_NODES * 128 * 2;
    unsigned short* Tsrc = (unsigned short*)(base + o); o += (size_t)N_NODES * 128 * 2;
    float* h1     = (float*)(base + o); o += (size_t)N_NODES * D * 4;
    float* h2     = (float*)(base + o); o += (size_t)N_NODES * D * 4;
    float* pooled = (float*)(base + o); o += (size_t)N_GRAPHS * D * 4;
    int* deg  = (int*)(base + o); o += (size_t)N_NODES * 4;
    int* off  = (int*)(base + o); o += (size_t)(N_NODES + 1) * 4;
    int* tsum = (int*)(base + o); o += 256 * 4;
    int* perm = (int*)(base + o); o += (size_t)N_EDGES * 4;
    int* src_sorted = (int*)(base + o); o += (size_t)N_EDGES * 4;
    int* dst_sorted = (int*)(base + o); o += (size_t)N_EDGES * 4;

    // ---- CSR build ----
    hipMemsetAsync(deg, 0, (size_t)N_NODES * 4, stream);
    hist_kernel<<<N_EDGES / 256, 256, 0, stream>>>(ei, deg);
    scan1<<<NB_SCAN, 256, 0, stream>>>(deg, off, tsum);
    scan2<<<1, 256, 0, stream>>>(tsum);
    scan3<<<NB_SCAN, 256, 0, stream>>>(off, tsum);
    hipMemsetAsync(deg, 0, (size_t)N_NODES * 4, stream);
    scatter_kernel<<<N_EDGES / 256, 256, 0, stream>>>(ei, off, deg, perm,
                                                      src_sorted, dst_sorted);

    // ---- layer 1 ----
    node_transform_mfma<<<3125, 256, 0, stream>>>(x, Wf1, Ws1, bf1, bs1, Tdst, Tsrc);
    hipMemcpyAsync(h1, x, (size_t)N_NODES * D * 4, hipMemcpyDeviceToDevice, stream);
    edge_message_mfma<<<3125, 256, 0, stream>>>(Tdst, Tsrc, ea, perm,
                                                src_sorted, dst_sorted, Wf1, Ws1, h1);

    // ---- layer 2 ----
    node_transform_mfma<<<3125, 256, 0, stream>>>(h1, Wf2, Ws2, bf2, bs2, Tdst, Tsrc);
    hipMemcpyAsync(h2, h1, (size_t)N_NODES * D * 4, hipMemcpyDeviceToDevice, stream);
    edge_message_mfma<<<3125, 256, 0, stream>>>(Tdst, Tsrc, ea, perm,
                                                src_sorted, dst_sorted, Wf2, Ws2, h2);

    // ---- pool + out ----
    hipMemsetAsync(pooled, 0, (size_t)N_GRAPHS * D * 4, stream);
    pool_kernel<<<12500, 256, 0, stream>>>(h2, batch, pooled);
    out_kernel<<<2, 256, 0, stream>>>(pooled, Wout, bout, out);
}